// Round 11
// baseline (219.586 us; speedup 1.0000x reference)
//
#include <hip/hip_runtime.h>

#define NN 50000
#define NE 800000
#define DD 128
#define NSTRIP 3125   // NN/16
#define NB 196        // dst>>8 buckets (49999>>8 == 195)
#define CHUNK 4096    // edges per shuf block; grid = ceil(NE/CHUNK) = 196
#define MAXB 6144     // bucket capacity (mean 4096, sigma ~64 -> +32 sigma)

// workspace layout, element (4-byte word) offsets
#define OF_BCUR  0            // int[256] bucket cursors/counts
#define OF_DINV  256          // float[NN]
#define OF_OFFS2 50432        // int2[NN] per-node (start,end) into padded csru
#define OF_TMP   150528       // uint[256*MAXB] padded buckets of (src<<8|dstlow)
#define OF_CSRU  1723392      // ushort[256*MAXB] padded sorted src
#define OF_G     2509824      // ushort[NN*DD] bf16 g = dinv*h, row-major 256B rows
#define OF_X2    5709824      // float[NN*DD] layer-2 input
#define OF_W1H   12109824     // ushort[16384] fragment order
#define OF_W1L   12118016
#define OF_W2H   12126208
#define OF_W2L   12134400     // end 12142592 words = 48.6 MB

typedef __attribute__((ext_vector_type(8))) short bf8_t;   // 8 bf16 = 4 VGPRs
typedef __attribute__((ext_vector_type(8))) unsigned short us8;
typedef __attribute__((ext_vector_type(4))) float f32x4;

static __device__ __forceinline__ unsigned short f2bf(float f) {
    unsigned int u = __float_as_uint(f);
    unsigned int r = (u + 0x7fffu + ((u >> 16) & 1u)) >> 16;   // RNE
    return (unsigned short)r;
}
static __device__ __forceinline__ float bf2f(unsigned short h) {
    return __uint_as_float(((unsigned int)h) << 16);
}

// both W conversions in one launch; block 0 also zeroes the bucket cursors.
// frag g=(ntile*4+kk)*64+lane holds B[k=kk*32+(lane>>4)*8+j][n=ntile*16+(lane&15)]
__global__ void k_wconv(const float* __restrict__ W1, const float* __restrict__ W2,
                        ushort* __restrict__ w1h, ushort* __restrict__ w1l,
                        ushort* __restrict__ w2h, ushort* __restrict__ w2l,
                        int* __restrict__ bcur) {
    if (blockIdx.x == 0) bcur[threadIdx.x] = 0;
    int gg = blockIdx.x * 256 + threadIdx.x;
    const float* W = (gg < 2048) ? W1 : W2;
    ushort* wh = (gg < 2048) ? w1h : w2h;
    ushort* wl = (gg < 2048) ? w1l : w2l;
    int g = gg & 2047;
    int ntile = g >> 8;
    int kk = (g >> 6) & 3;
    int lane = g & 63;
    int k0 = kk * 32 + ((lane >> 4) * 8);
    int col = ntile * 16 + (lane & 15);
#pragma unroll
    for (int j = 0; j < 8; ++j) {
        float w = W[(k0 + j) * DD + col];
        unsigned short h = f2bf(w);
        wh[(size_t)g * 8 + j] = h;
        wl[(size_t)g * 8 + j] = f2bf(w - bf2f(h));
    }
}

// shuffle edges into padded coarse buckets.  Per block: LDS histogram of its
// chunk, ONE global atomic per touched bucket reserves a contiguous run in
// tmp[b*MAXB ...], then packed entries are written -> per-block contiguous
// runs (lines written by a single block -> no cross-XCD bouncing).
// After all blocks: bcur[b] == final bucket count (no separate hist pass).
__global__ void k_shuf(const int* __restrict__ src, const int* __restrict__ dst,
                       int* __restrict__ bcur, unsigned int* __restrict__ tmp) {
    __shared__ int lcnt[256];
    __shared__ int lbase[256];
    __shared__ int lcur[256];
    int tid = threadIdx.x;
    lcnt[tid] = 0;
    __syncthreads();
    int e0 = blockIdx.x * CHUNK;
    int e1 = e0 + CHUNK; if (e1 > NE) e1 = NE;
    for (int e = e0 + tid; e < e1; e += 256)
        atomicAdd(&lcnt[dst[e] >> 8], 1);
    __syncthreads();
    if (lcnt[tid]) lbase[tid] = atomicAdd(&bcur[tid], lcnt[tid]);
    lcur[tid] = 0;
    __syncthreads();
    for (int e = e0 + tid; e < e1; e += 256) {
        int d = dst[e], s = src[e];
        int b = d >> 8;
        int r = atomicAdd(&lcur[b], 1);
        tmp[(size_t)b * MAXB + lbase[b] + r] =
            ((unsigned int)s << 8) | (unsigned int)(d & 255);
    }
}

// per-bucket LDS counting sort -> padded CSR slab, per-node (start,end), dinv.
__global__ __launch_bounds__(256) void k_sort(const int* __restrict__ bcur,
                                              const unsigned int* __restrict__ tmp,
                                              ushort* __restrict__ csru,
                                              int2* __restrict__ offs2,
                                              float* __restrict__ dinv) {
    __shared__ unsigned int ent[MAXB];
    __shared__ int cnt[256];
    __shared__ int boff[256];
    __shared__ int cur[256];
    int b = blockIdx.x, tid = threadIdx.x;
    int base = b * MAXB;
    int nb = bcur[b];
    cnt[tid] = 0;
    __syncthreads();
    for (int i = tid; i < nb; i += 256) {
        unsigned int v = tmp[base + i];
        ent[i] = v;
        atomicAdd(&cnt[v & 255], 1);
    }
    __syncthreads();
    int v = cnt[tid];
    boff[tid] = v;
    __syncthreads();
    for (int o = 1; o < 256; o <<= 1) {
        int t = (tid >= o) ? boff[tid - o] : 0;
        __syncthreads();
        boff[tid] += t;
        __syncthreads();
    }
    int excl = boff[tid] - v;
    int node = b * 256 + tid;
    if (node < NN) {
        offs2[node] = make_int2(base + excl, base + excl + v);
        dinv[node] = rsqrtf((float)(v + 1));   // +1 self-loop
    }
    cur[tid] = excl;
    __syncthreads();
    for (int i = tid; i < nb; i += 256) {
        unsigned int e = ent[i];
        int bin = e & 255;
        int r = atomicAdd(&cur[bin], 1);
        csru[base + r] = (ushort)(e >> 8);
    }
}

// MFMA GEMM, split-bf16 (hi*hi + hi*lo + lo*hi ~ fp32 accuracy).
// Reads fp32 X directly, Dekker-splits in-register.
// Epilogue scales rows by dinv, stores bf16 g row-major (256B rows).
__global__ __launch_bounds__(256) void k_mgemm(const float* __restrict__ X,
                                               const ushort* __restrict__ wh,
                                               const ushort* __restrict__ wl,
                                               const float* __restrict__ dinv,
                                               ushort* __restrict__ G) {
    int wave = threadIdx.x >> 6;
    int lane = threadIdx.x & 63;
    int strip = blockIdx.x * 4 + wave;
    if (strip >= NSTRIP) return;
    int rb = strip << 4;
    int m = lane & 15;
    int quad = lane >> 4;
    const float* ar = X + (size_t)(rb + m) * DD;
    f32x4 acc[8];
#pragma unroll
    for (int t = 0; t < 8; ++t) acc[t] = (f32x4){0.f, 0.f, 0.f, 0.f};
#pragma unroll
    for (int kk = 0; kk < 4; ++kk) {
        float4 xa = *(const float4*)(ar + kk * 32 + quad * 8);
        float4 xb = *(const float4*)(ar + kk * 32 + quad * 8 + 4);
        float xs[8] = {xa.x, xa.y, xa.z, xa.w, xb.x, xb.y, xb.z, xb.w};
        bf8_t ah, al;
#pragma unroll
        for (int j = 0; j < 8; ++j) {
            unsigned short hh = f2bf(xs[j]);
            ah[j] = (short)hh;
            al[j] = (short)f2bf(xs[j] - bf2f(hh));
        }
#pragma unroll
        for (int t = 0; t < 8; ++t) {
            size_t bo = ((size_t)(t * 4 + kk) * 64 + lane) * 8;
            bf8_t bh = *(const bf8_t*)(wh + bo);
            bf8_t bl = *(const bf8_t*)(wl + bo);
            acc[t] = __builtin_amdgcn_mfma_f32_16x16x32_bf16(ah, bh, acc[t], 0, 0, 0);
            acc[t] = __builtin_amdgcn_mfma_f32_16x16x32_bf16(ah, bl, acc[t], 0, 0, 0);
            acc[t] = __builtin_amdgcn_mfma_f32_16x16x32_bf16(al, bh, acc[t], 0, 0, 0);
        }
    }
    // C/D layout (m89-verified): col = lane&15, row = quad*4 + reg
    float dv[4];
#pragma unroll
    for (int r = 0; r < 4; ++r) dv[r] = dinv[rb + quad * 4 + r];
#pragma unroll
    for (int t = 0; t < 8; ++t) {
#pragma unroll
        for (int r = 0; r < 4; ++r)
            G[(size_t)(rb + quad * 4 + r) * DD + t * 16 + m] = f2bf(dv[r] * acc[t][r]);
    }
}

// out[i] = relu( dinv[i] * ( sum_{e: dst==i} g[src_e] + g[i] ) + bias )
// One wave per node.  4 quarter-waves of 16 lanes x ushort8 (16B/lane = one
// full 256B row per quarter); quarters take interleaved edge slots; 4x
// unroll -> up to 16 independent row gathers in flight per wave.
// Cross-quarter reduce via shfl_xor(16) + shfl_xor(32).
__global__ void k_agg(const ushort* __restrict__ g, const float* __restrict__ dinv,
                      const int2* __restrict__ offs2, const ushort* __restrict__ csru,
                      const float* __restrict__ bias, float* __restrict__ outf) {
    int wave = threadIdx.x >> 6;
    int lane = threadIdx.x & 63;
    int node = blockIdx.x * 4 + wave;   // grid = NN/4 exactly
    int q = lane >> 4;
    int l = lane & 15;
    float a0[8] = {0.f, 0.f, 0.f, 0.f, 0.f, 0.f, 0.f, 0.f};
    float a1[8] = {0.f, 0.f, 0.f, 0.f, 0.f, 0.f, 0.f, 0.f};
    float a2[8] = {0.f, 0.f, 0.f, 0.f, 0.f, 0.f, 0.f, 0.f};
    float a3[8] = {0.f, 0.f, 0.f, 0.f, 0.f, 0.f, 0.f, 0.f};
    int2 oe = offs2[node];
    int e  = oe.x + q;
    int e1 = oe.y;
    for (; e + 12 < e1; e += 16) {
        int s0 = csru[e];
        int s1 = csru[e + 4];
        int s2 = csru[e + 8];
        int s3 = csru[e + 12];
        us8 v0 = *(const us8*)(g + (size_t)s0 * DD + 8 * l);
        us8 v1 = *(const us8*)(g + (size_t)s1 * DD + 8 * l);
        us8 v2 = *(const us8*)(g + (size_t)s2 * DD + 8 * l);
        us8 v3 = *(const us8*)(g + (size_t)s3 * DD + 8 * l);
#pragma unroll
        for (int j = 0; j < 8; ++j) {
            a0[j] += bf2f(v0[j]);
            a1[j] += bf2f(v1[j]);
            a2[j] += bf2f(v2[j]);
            a3[j] += bf2f(v3[j]);
        }
    }
    for (; e < e1; e += 4) {
        int s0 = csru[e];
        us8 v0 = *(const us8*)(g + (size_t)s0 * DD + 8 * l);
#pragma unroll
        for (int j = 0; j < 8; ++j) a0[j] += bf2f(v0[j]);
    }
    if (q == 0) {  // self-loop term: dinv^2*h = dinv*g, counted once
        us8 v = *(const us8*)(g + (size_t)node * DD + 8 * l);
#pragma unroll
        for (int j = 0; j < 8; ++j) a0[j] += bf2f(v[j]);
    }
#pragma unroll
    for (int j = 0; j < 8; ++j) {
        a0[j] += a1[j] + a2[j] + a3[j];
        a0[j] += __shfl_xor(a0[j], 16, 64);
        a0[j] += __shfl_xor(a0[j], 32, 64);
    }
    if (q == 0) {
        float di = dinv[node];
        float* op = outf + (size_t)node * DD + 8 * l;
        const float* bp = bias + 8 * l;
        float4 o0, o1;
        o0.x = fmaxf(di * a0[0] + bp[0], 0.f);
        o0.y = fmaxf(di * a0[1] + bp[1], 0.f);
        o0.z = fmaxf(di * a0[2] + bp[2], 0.f);
        o0.w = fmaxf(di * a0[3] + bp[3], 0.f);
        o1.x = fmaxf(di * a0[4] + bp[4], 0.f);
        o1.y = fmaxf(di * a0[5] + bp[5], 0.f);
        o1.z = fmaxf(di * a0[6] + bp[6], 0.f);
        o1.w = fmaxf(di * a0[7] + bp[7], 0.f);
        *(float4*)op = o0;
        *(float4*)(op + 4) = o1;
    }
}

extern "C" void kernel_launch(void* const* d_in, const int* in_sizes, int n_in,
                              void* d_out, int out_size, void* d_ws, size_t ws_size,
                              hipStream_t stream) {
    const float* x  = (const float*)d_in[0];
    const int*   ei = (const int*)d_in[1];
    const float* W1 = (const float*)d_in[2];
    const float* b1 = (const float*)d_in[3];
    const float* W2 = (const float*)d_in[4];
    const float* b2 = (const float*)d_in[5];
    float* out = (float*)d_out;

    const int* src = ei;        // edge_index[0]
    const int* dst = ei + NE;   // edge_index[1]

    int*          wsi  = (int*)d_ws;
    float*        wsf  = (float*)d_ws;
    ushort*       wsu  = (ushort*)d_ws;
    unsigned int* wsuw = (unsigned int*)d_ws;
    int*    bcur  = wsi + OF_BCUR;
    float*  dinv  = wsf + OF_DINV;
    int2*   offs2 = (int2*)(wsi + OF_OFFS2);
    unsigned int* tmp = wsuw + OF_TMP;
    ushort* csru  = wsu + (size_t)OF_CSRU * 2;
    ushort* gbuf  = wsu + (size_t)OF_G * 2;
    float*  x2    = wsf + OF_X2;
    ushort* w1h   = wsu + (size_t)OF_W1H * 2;
    ushort* w1l   = wsu + (size_t)OF_W1L * 2;
    ushort* w2h   = wsu + (size_t)OF_W2H * 2;
    ushort* w2l   = wsu + (size_t)OF_W2L * 2;

    const int chunks = (NE + CHUNK - 1) / CHUNK;  // 196

    // W conversions + bcur zeroing, then 2-pass padded bucket-sort CSR build
    hipLaunchKernelGGL(k_wconv, dim3(16), dim3(256), 0, stream,
                       W1, W2, w1h, w1l, w2h, w2l, bcur);
    hipLaunchKernelGGL(k_shuf,  dim3(chunks), dim3(256), 0, stream, src, dst, bcur, tmp);
    hipLaunchKernelGGL(k_sort,  dim3(NB), dim3(256), 0, stream, bcur, tmp, csru, offs2, dinv);

    const int gblocks = (NSTRIP + 3) / 4;  // 782

    // layer 1: g = dinv*(x @ W1) (MFMA, bf16) ; agg -> relu(dinv*sum + b1) fp32
    hipLaunchKernelGGL(k_mgemm, dim3(gblocks), dim3(256), 0, stream, x, w1h, w1l, dinv, gbuf);
    hipLaunchKernelGGL(k_agg,   dim3(NN / 4), dim3(256), 0, stream,
                       gbuf, dinv, offs2, csru, b1, x2);
    // layer 2
    hipLaunchKernelGGL(k_mgemm, dim3(gblocks), dim3(256), 0, stream, x2, w2h, w2l, dinv, gbuf);
    hipLaunchKernelGGL(k_agg,   dim3(NN / 4), dim3(256), 0, stream,
                       gbuf, dinv, offs2, csru, b2, out);
}

// Round 12
// 214.053 us; speedup vs baseline: 1.0258x; 1.0258x over previous
//
#include <hip/hip_runtime.h>

#define NN 50000
#define NE 800000
#define DD 128
#define NSTRIP 3125   // NN/16
#define NB 196        // dst>>8 buckets (49999>>8 == 195)
#define CHUNK 4096    // edges per shuf block; grid = ceil(NE/CHUNK) = 196
#define MAXB 6144     // bucket capacity (mean 4096, sigma ~64 -> +32 sigma)

// workspace layout, element (4-byte word) offsets
#define OF_BCUR  0            // int[256] bucket cursors/counts
#define OF_DINV  256          // float[NN]
#define OF_OFFS2 50432        // int2[NN] per-node (start,end) into padded csru
#define OF_TMP   150528       // uint[256*MAXB] padded buckets of (src<<8|dstlow)
#define OF_CSRU  1723392      // ushort[256*MAXB] padded sorted src
#define OF_G1    2509824      // ushort[NN*DD] bf16 g1 = dinv*(x@W1)
#define OF_G2    5709824      // ushort[NN*DD] bf16 g2 = dinv*(relu(agg1)@W2)
#define OF_W1H   8909824      // ushort[16384] fragment order
#define OF_W1L   8918016
#define OF_W2H   8926208
#define OF_W2L   8934400      // end 8942592 words = 35.8 MB

typedef __attribute__((ext_vector_type(8))) short bf8_t;   // 8 bf16 = 4 VGPRs
typedef __attribute__((ext_vector_type(8))) unsigned short us8;
typedef __attribute__((ext_vector_type(4))) float f32x4;

static __device__ __forceinline__ unsigned short f2bf(float f) {
    unsigned int u = __float_as_uint(f);
    unsigned int r = (u + 0x7fffu + ((u >> 16) & 1u)) >> 16;   // RNE
    return (unsigned short)r;
}
static __device__ __forceinline__ float bf2f(unsigned short h) {
    return __uint_as_float(((unsigned int)h) << 16);
}

// both W conversions in one launch; block 0 also zeroes the bucket cursors.
// frag g=(ntile*4+kk)*64+lane holds B[k=kk*32+(lane>>4)*8+j][n=ntile*16+(lane&15)]
__global__ void k_wconv(const float* __restrict__ W1, const float* __restrict__ W2,
                        ushort* __restrict__ w1h, ushort* __restrict__ w1l,
                        ushort* __restrict__ w2h, ushort* __restrict__ w2l,
                        int* __restrict__ bcur) {
    if (blockIdx.x == 0) bcur[threadIdx.x] = 0;
    int gg = blockIdx.x * 256 + threadIdx.x;
    const float* W = (gg < 2048) ? W1 : W2;
    ushort* wh = (gg < 2048) ? w1h : w2h;
    ushort* wl = (gg < 2048) ? w1l : w2l;
    int g = gg & 2047;
    int ntile = g >> 8;
    int kk = (g >> 6) & 3;
    int lane = g & 63;
    int k0 = kk * 32 + ((lane >> 4) * 8);
    int col = ntile * 16 + (lane & 15);
#pragma unroll
    for (int j = 0; j < 8; ++j) {
        float w = W[(k0 + j) * DD + col];
        unsigned short h = f2bf(w);
        wh[(size_t)g * 8 + j] = h;
        wl[(size_t)g * 8 + j] = f2bf(w - bf2f(h));
    }
}

// shuffle edges into padded coarse buckets.  Per block: LDS histogram of its
// chunk, ONE global atomic per touched bucket reserves a contiguous run in
// tmp[b*MAXB ...], then packed entries are written -> per-block contiguous
// runs (lines written by a single block -> no cross-XCD bouncing).
// After all blocks: bcur[b] == final bucket count.
__global__ void k_shuf(const int* __restrict__ src, const int* __restrict__ dst,
                       int* __restrict__ bcur, unsigned int* __restrict__ tmp) {
    __shared__ int lcnt[256];
    __shared__ int lbase[256];
    __shared__ int lcur[256];
    int tid = threadIdx.x;
    lcnt[tid] = 0;
    __syncthreads();
    int e0 = blockIdx.x * CHUNK;
    int e1 = e0 + CHUNK; if (e1 > NE) e1 = NE;
    for (int e = e0 + tid; e < e1; e += 256)
        atomicAdd(&lcnt[dst[e] >> 8], 1);
    __syncthreads();
    if (lcnt[tid]) lbase[tid] = atomicAdd(&bcur[tid], lcnt[tid]);
    lcur[tid] = 0;
    __syncthreads();
    for (int e = e0 + tid; e < e1; e += 256) {
        int d = dst[e], s = src[e];
        int b = d >> 8;
        int r = atomicAdd(&lcur[b], 1);
        tmp[(size_t)b * MAXB + lbase[b] + r] =
            ((unsigned int)s << 8) | (unsigned int)(d & 255);
    }
}

// per-bucket LDS counting sort -> padded CSR slab, per-node (start,end), dinv.
__global__ __launch_bounds__(256) void k_sort(const int* __restrict__ bcur,
                                              const unsigned int* __restrict__ tmp,
                                              ushort* __restrict__ csru,
                                              int2* __restrict__ offs2,
                                              float* __restrict__ dinv) {
    __shared__ unsigned int ent[MAXB];
    __shared__ int cnt[256];
    __shared__ int boff[256];
    __shared__ int cur[256];
    int b = blockIdx.x, tid = threadIdx.x;
    int base = b * MAXB;
    int nb = bcur[b];
    cnt[tid] = 0;
    __syncthreads();
    for (int i = tid; i < nb; i += 256) {
        unsigned int v = tmp[base + i];
        ent[i] = v;
        atomicAdd(&cnt[v & 255], 1);
    }
    __syncthreads();
    int v = cnt[tid];
    boff[tid] = v;
    __syncthreads();
    for (int o = 1; o < 256; o <<= 1) {
        int t = (tid >= o) ? boff[tid - o] : 0;
        __syncthreads();
        boff[tid] += t;
        __syncthreads();
    }
    int excl = boff[tid] - v;
    int node = b * 256 + tid;
    if (node < NN) {
        offs2[node] = make_int2(base + excl, base + excl + v);
        dinv[node] = rsqrtf((float)(v + 1));   // +1 self-loop
    }
    cur[tid] = excl;
    __syncthreads();
    for (int i = tid; i < nb; i += 256) {
        unsigned int e = ent[i];
        int bin = e & 255;
        int r = atomicAdd(&cur[bin], 1);
        csru[base + r] = (ushort)(e >> 8);
    }
}

// MFMA GEMM, split-bf16 (hi*hi + hi*lo + lo*hi ~ fp32 accuracy).
// Reads fp32 X directly, Dekker-splits in-register.
// Epilogue scales rows by dinv, stores bf16 g row-major (256B rows).
__global__ __launch_bounds__(256) void k_mgemm(const float* __restrict__ X,
                                               const ushort* __restrict__ wh,
                                               const ushort* __restrict__ wl,
                                               const float* __restrict__ dinv,
                                               ushort* __restrict__ G) {
    int wave = threadIdx.x >> 6;
    int lane = threadIdx.x & 63;
    int strip = blockIdx.x * 4 + wave;
    if (strip >= NSTRIP) return;
    int rb = strip << 4;
    int m = lane & 15;
    int quad = lane >> 4;
    const float* ar = X + (size_t)(rb + m) * DD;
    f32x4 acc[8];
#pragma unroll
    for (int t = 0; t < 8; ++t) acc[t] = (f32x4){0.f, 0.f, 0.f, 0.f};
#pragma unroll
    for (int kk = 0; kk < 4; ++kk) {
        float4 xa = *(const float4*)(ar + kk * 32 + quad * 8);
        float4 xb = *(const float4*)(ar + kk * 32 + quad * 8 + 4);
        float xs[8] = {xa.x, xa.y, xa.z, xa.w, xb.x, xb.y, xb.z, xb.w};
        bf8_t ah, al;
#pragma unroll
        for (int j = 0; j < 8; ++j) {
            unsigned short hh = f2bf(xs[j]);
            ah[j] = (short)hh;
            al[j] = (short)f2bf(xs[j] - bf2f(hh));
        }
#pragma unroll
        for (int t = 0; t < 8; ++t) {
            size_t bo = ((size_t)(t * 4 + kk) * 64 + lane) * 8;
            bf8_t bh = *(const bf8_t*)(wh + bo);
            bf8_t bl = *(const bf8_t*)(wl + bo);
            acc[t] = __builtin_amdgcn_mfma_f32_16x16x32_bf16(ah, bh, acc[t], 0, 0, 0);
            acc[t] = __builtin_amdgcn_mfma_f32_16x16x32_bf16(ah, bl, acc[t], 0, 0, 0);
            acc[t] = __builtin_amdgcn_mfma_f32_16x16x32_bf16(al, bh, acc[t], 0, 0, 0);
        }
    }
    // C/D layout (m89-verified): col = lane&15, row = quad*4 + reg
    float dv[4];
#pragma unroll
    for (int r = 0; r < 4; ++r) dv[r] = dinv[rb + quad * 4 + r];
#pragma unroll
    for (int t = 0; t < 8; ++t) {
#pragma unroll
        for (int r = 0; r < 4; ++r)
            G[(size_t)(rb + quad * 4 + r) * DD + t * 16 + m] = f2bf(dv[r] * acc[t][r]);
    }
}

// FUSED layer-1 aggregation + layer-2 GEMM.  One block = 16 nodes.
// Phase 1 (agg): 4 waves x 4 nodes; per node the k_agg inner loop (4 quarter-
// waves x ushort8, 4x unroll = 16 gathers in flight); x2 row = relu(dinv*sum
// + b1) written to padded LDS (132-float rows -> only 2-way bank alias).
// Phase 2 (gemm): barrier, then the same waves MFMA the 16x128 LDS strip
// against W2 (2 N-tiles/wave), scale by dinv, store bf16 g2.
__global__ __launch_bounds__(256) void k_aggmm(const ushort* __restrict__ g1,
                                               const float* __restrict__ dinv,
                                               const int2* __restrict__ offs2,
                                               const ushort* __restrict__ csru,
                                               const float* __restrict__ b1,
                                               const ushort* __restrict__ w2h,
                                               const ushort* __restrict__ w2l,
                                               ushort* __restrict__ g2) {
    __shared__ float xs[16][132];
    int wave = threadIdx.x >> 6;
    int lane = threadIdx.x & 63;
    int rb = blockIdx.x * 16;
    int q = lane >> 4;
    int l = lane & 15;
    const float* bp = b1 + 8 * l;
    // ---- phase 1: aggregate 4 nodes per wave ----
    for (int nn = 0; nn < 4; ++nn) {
        int node = rb + wave * 4 + nn;
        float a0[8] = {0.f, 0.f, 0.f, 0.f, 0.f, 0.f, 0.f, 0.f};
        float a1[8] = {0.f, 0.f, 0.f, 0.f, 0.f, 0.f, 0.f, 0.f};
        float a2[8] = {0.f, 0.f, 0.f, 0.f, 0.f, 0.f, 0.f, 0.f};
        float a3[8] = {0.f, 0.f, 0.f, 0.f, 0.f, 0.f, 0.f, 0.f};
        int2 oe = offs2[node];
        int e  = oe.x + q;
        int e1 = oe.y;
        for (; e + 12 < e1; e += 16) {
            int s0 = csru[e];
            int s1 = csru[e + 4];
            int s2 = csru[e + 8];
            int s3 = csru[e + 12];
            us8 v0 = *(const us8*)(g1 + (size_t)s0 * DD + 8 * l);
            us8 v1 = *(const us8*)(g1 + (size_t)s1 * DD + 8 * l);
            us8 v2 = *(const us8*)(g1 + (size_t)s2 * DD + 8 * l);
            us8 v3 = *(const us8*)(g1 + (size_t)s3 * DD + 8 * l);
#pragma unroll
            for (int j = 0; j < 8; ++j) {
                a0[j] += bf2f(v0[j]);
                a1[j] += bf2f(v1[j]);
                a2[j] += bf2f(v2[j]);
                a3[j] += bf2f(v3[j]);
            }
        }
        for (; e < e1; e += 4) {
            int s0 = csru[e];
            us8 v0 = *(const us8*)(g1 + (size_t)s0 * DD + 8 * l);
#pragma unroll
            for (int j = 0; j < 8; ++j) a0[j] += bf2f(v0[j]);
        }
        if (q == 0) {  // self-loop term
            us8 v = *(const us8*)(g1 + (size_t)node * DD + 8 * l);
#pragma unroll
            for (int j = 0; j < 8; ++j) a0[j] += bf2f(v[j]);
        }
#pragma unroll
        for (int j = 0; j < 8; ++j) {
            a0[j] += a1[j] + a2[j] + a3[j];
            a0[j] += __shfl_xor(a0[j], 16, 64);
            a0[j] += __shfl_xor(a0[j], 32, 64);
        }
        if (q == 0) {
            float di = dinv[node];
            float* xr = &xs[wave * 4 + nn][8 * l];
#pragma unroll
            for (int j = 0; j < 8; ++j)
                xr[j] = fmaxf(di * a0[j] + bp[j], 0.f);
        }
    }
    __syncthreads();
    // ---- phase 2: 16x128 strip @ W2, 2 N-tiles per wave ----
    int m = lane & 15;
    int quad = lane >> 4;
    f32x4 acc[2];
    acc[0] = (f32x4){0.f, 0.f, 0.f, 0.f};
    acc[1] = (f32x4){0.f, 0.f, 0.f, 0.f};
#pragma unroll
    for (int kk = 0; kk < 4; ++kk) {
        const float* xr = &xs[m][kk * 32 + quad * 8];
        float4 xa = *(const float4*)xr;
        float4 xb = *(const float4*)(xr + 4);
        float xv[8] = {xa.x, xa.y, xa.z, xa.w, xb.x, xb.y, xb.z, xb.w};
        bf8_t ah, al;
#pragma unroll
        for (int j = 0; j < 8; ++j) {
            unsigned short hh = f2bf(xv[j]);
            ah[j] = (short)hh;
            al[j] = (short)f2bf(xv[j] - bf2f(hh));
        }
#pragma unroll
        for (int tt = 0; tt < 2; ++tt) {
            int t = wave * 2 + tt;
            size_t bo = ((size_t)(t * 4 + kk) * 64 + lane) * 8;
            bf8_t bh = *(const bf8_t*)(w2h + bo);
            bf8_t bl = *(const bf8_t*)(w2l + bo);
            acc[tt] = __builtin_amdgcn_mfma_f32_16x16x32_bf16(ah, bh, acc[tt], 0, 0, 0);
            acc[tt] = __builtin_amdgcn_mfma_f32_16x16x32_bf16(ah, bl, acc[tt], 0, 0, 0);
            acc[tt] = __builtin_amdgcn_mfma_f32_16x16x32_bf16(al, bh, acc[tt], 0, 0, 0);
        }
    }
    float dv[4];
#pragma unroll
    for (int r = 0; r < 4; ++r) dv[r] = dinv[rb + quad * 4 + r];
#pragma unroll
    for (int tt = 0; tt < 2; ++tt) {
        int t = wave * 2 + tt;
#pragma unroll
        for (int r = 0; r < 4; ++r)
            g2[(size_t)(rb + quad * 4 + r) * DD + t * 16 + m] = f2bf(dv[r] * acc[tt][r]);
    }
}

// final aggregation: out[i] = relu( dinv[i]*(sum g2[src] + g2[i]) + b2 )
__global__ void k_agg(const ushort* __restrict__ g, const float* __restrict__ dinv,
                      const int2* __restrict__ offs2, const ushort* __restrict__ csru,
                      const float* __restrict__ bias, float* __restrict__ outf) {
    int wave = threadIdx.x >> 6;
    int lane = threadIdx.x & 63;
    int node = blockIdx.x * 4 + wave;   // grid = NN/4 exactly
    int q = lane >> 4;
    int l = lane & 15;
    float a0[8] = {0.f, 0.f, 0.f, 0.f, 0.f, 0.f, 0.f, 0.f};
    float a1[8] = {0.f, 0.f, 0.f, 0.f, 0.f, 0.f, 0.f, 0.f};
    float a2[8] = {0.f, 0.f, 0.f, 0.f, 0.f, 0.f, 0.f, 0.f};
    float a3[8] = {0.f, 0.f, 0.f, 0.f, 0.f, 0.f, 0.f, 0.f};
    int2 oe = offs2[node];
    int e  = oe.x + q;
    int e1 = oe.y;
    for (; e + 12 < e1; e += 16) {
        int s0 = csru[e];
        int s1 = csru[e + 4];
        int s2 = csru[e + 8];
        int s3 = csru[e + 12];
        us8 v0 = *(const us8*)(g + (size_t)s0 * DD + 8 * l);
        us8 v1 = *(const us8*)(g + (size_t)s1 * DD + 8 * l);
        us8 v2 = *(const us8*)(g + (size_t)s2 * DD + 8 * l);
        us8 v3 = *(const us8*)(g + (size_t)s3 * DD + 8 * l);
#pragma unroll
        for (int j = 0; j < 8; ++j) {
            a0[j] += bf2f(v0[j]);
            a1[j] += bf2f(v1[j]);
            a2[j] += bf2f(v2[j]);
            a3[j] += bf2f(v3[j]);
        }
    }
    for (; e < e1; e += 4) {
        int s0 = csru[e];
        us8 v0 = *(const us8*)(g + (size_t)s0 * DD + 8 * l);
#pragma unroll
        for (int j = 0; j < 8; ++j) a0[j] += bf2f(v0[j]);
    }
    if (q == 0) {  // self-loop term
        us8 v = *(const us8*)(g + (size_t)node * DD + 8 * l);
#pragma unroll
        for (int j = 0; j < 8; ++j) a0[j] += bf2f(v[j]);
    }
#pragma unroll
    for (int j = 0; j < 8; ++j) {
        a0[j] += a1[j] + a2[j] + a3[j];
        a0[j] += __shfl_xor(a0[j], 16, 64);
        a0[j] += __shfl_xor(a0[j], 32, 64);
    }
    if (q == 0) {
        float di = dinv[node];
        float* op = outf + (size_t)node * DD + 8 * l;
        const float* bp = bias + 8 * l;
        float4 o0, o1;
        o0.x = fmaxf(di * a0[0] + bp[0], 0.f);
        o0.y = fmaxf(di * a0[1] + bp[1], 0.f);
        o0.z = fmaxf(di * a0[2] + bp[2], 0.f);
        o0.w = fmaxf(di * a0[3] + bp[3], 0.f);
        o1.x = fmaxf(di * a0[4] + bp[4], 0.f);
        o1.y = fmaxf(di * a0[5] + bp[5], 0.f);
        o1.z = fmaxf(di * a0[6] + bp[6], 0.f);
        o1.w = fmaxf(di * a0[7] + bp[7], 0.f);
        *(float4*)op = o0;
        *(float4*)(op + 4) = o1;
    }
}

extern "C" void kernel_launch(void* const* d_in, const int* in_sizes, int n_in,
                              void* d_out, int out_size, void* d_ws, size_t ws_size,
                              hipStream_t stream) {
    const float* x  = (const float*)d_in[0];
    const int*   ei = (const int*)d_in[1];
    const float* W1 = (const float*)d_in[2];
    const float* b1 = (const float*)d_in[3];
    const float* W2 = (const float*)d_in[4];
    const float* b2 = (const float*)d_in[5];
    float* out = (float*)d_out;

    const int* src = ei;        // edge_index[0]
    const int* dst = ei + NE;   // edge_index[1]

    int*          wsi  = (int*)d_ws;
    float*        wsf  = (float*)d_ws;
    ushort*       wsu  = (ushort*)d_ws;
    unsigned int* wsuw = (unsigned int*)d_ws;
    int*    bcur  = wsi + OF_BCUR;
    float*  dinv  = wsf + OF_DINV;
    int2*   offs2 = (int2*)(wsi + OF_OFFS2);
    unsigned int* tmp = wsuw + OF_TMP;
    ushort* csru  = wsu + (size_t)OF_CSRU * 2;
    ushort* g1    = wsu + (size_t)OF_G1 * 2;
    ushort* g2    = wsu + (size_t)OF_G2 * 2;
    ushort* w1h   = wsu + (size_t)OF_W1H * 2;
    ushort* w1l   = wsu + (size_t)OF_W1L * 2;
    ushort* w2h   = wsu + (size_t)OF_W2H * 2;
    ushort* w2l   = wsu + (size_t)OF_W2L * 2;

    const int chunks = (NE + CHUNK - 1) / CHUNK;  // 196

    hipLaunchKernelGGL(k_wconv, dim3(16), dim3(256), 0, stream,
                       W1, W2, w1h, w1l, w2h, w2l, bcur);
    hipLaunchKernelGGL(k_shuf,  dim3(chunks), dim3(256), 0, stream, src, dst, bcur, tmp);
    hipLaunchKernelGGL(k_sort,  dim3(NB), dim3(256), 0, stream, bcur, tmp, csru, offs2, dinv);

    const int gblocks = (NSTRIP + 3) / 4;  // 782

    // layer 1 GEMM: g1 = dinv*(x @ W1)
    hipLaunchKernelGGL(k_mgemm, dim3(gblocks), dim3(256), 0, stream, x, w1h, w1l, dinv, g1);
    // fused: agg(g1)+relu+b1 -> (LDS) -> @W2 -> g2 = dinv*(x2 @ W2)
    hipLaunchKernelGGL(k_aggmm, dim3(NSTRIP), dim3(256), 0, stream,
                       g1, dinv, offs2, csru, b1, w2h, w2l, g2);
    // final aggregation -> out
    hipLaunchKernelGGL(k_agg,   dim3(NN / 4), dim3(256), 0, stream,
                       g2, dinv, offs2, csru, b2, out);
}

// Round 13
// 208.047 us; speedup vs baseline: 1.0555x; 1.0289x over previous
//
#include <hip/hip_runtime.h>

#define NN 50000
#define NE 800000
#define DD 128
#define NSTRIP 3125   // NN/16
#define NB 196        // dst>>8 buckets (49999>>8 == 195)
#define CHUNK 4096    // edges per shuf block; 196 chunks
#define MAXB 6144     // bucket capacity (mean 4096, sigma ~64)

// workspace layout, element (4-byte word) offsets
#define OF_LCNT  0            // int[256*196] per-bucket-per-block counts, bucket-major
#define OF_LOFS  50176        // int[256*196] per-block local offsets, bucket-major
#define OF_DINV  100352       // float[NN]
#define OF_OFFS2 150528       // int2[NN] per-node (start,end) into padded csru
#define OF_TMP2  250624       // uint[196*CHUNK] block-major slabs, bucket-grouped
#define OF_CSRU  1053440      // ushort[196*MAXB] padded sorted src
#define OF_H1    1655552      // ushort[NN*DD] bf16 h1 = x@W1 (unscaled)
#define OF_H2    4855552      // ushort[NN*DD] bf16 h2 (unscaled)
#define OF_W1H   8055552      // ushort[16384] fragment order
#define OF_W1L   8063744
#define OF_W2H   8071936
#define OF_W2L   8080128      // end 8088320 words = 32.4 MB

typedef __attribute__((ext_vector_type(8))) short bf8_t;   // 8 bf16 = 4 VGPRs
typedef __attribute__((ext_vector_type(8))) unsigned short us8;
typedef __attribute__((ext_vector_type(4))) float f32x4;

static __device__ __forceinline__ unsigned short f2bf(float f) {
    unsigned int u = __float_as_uint(f);
    unsigned int r = (u + 0x7fffu + ((u >> 16) & 1u)) >> 16;   // RNE
    return (unsigned short)r;
}
static __device__ __forceinline__ float bf2f(unsigned short h) {
    return __uint_as_float(((unsigned int)h) << 16);
}

// W1+W2 -> bf16 hi/lo split in B-fragment-contiguous order.
// frag g=(ntile*4+kk)*64+lane holds B[k=kk*32+(lane>>4)*8+j][n=ntile*16+(lane&15)]
__global__ void k_wconv(const float* __restrict__ W1, const float* __restrict__ W2,
                        ushort* __restrict__ w1h, ushort* __restrict__ w1l,
                        ushort* __restrict__ w2h, ushort* __restrict__ w2l) {
    int gg = blockIdx.x * 256 + threadIdx.x;
    const float* W = (gg < 2048) ? W1 : W2;
    ushort* wh = (gg < 2048) ? w1h : w2h;
    ushort* wl = (gg < 2048) ? w1l : w2l;
    int g = gg & 2047;
    int ntile = g >> 8;
    int kk = (g >> 6) & 3;
    int lane = g & 63;
    int k0 = kk * 32 + ((lane >> 4) * 8);
    int col = ntile * 16 + (lane & 15);
#pragma unroll
    for (int j = 0; j < 8; ++j) {
        float w = W[(k0 + j) * DD + col];
        unsigned short h = f2bf(w);
        wh[(size_t)g * 8 + j] = h;
        wl[(size_t)g * 8 + j] = f2bf(w - bf2f(h));
    }
}

// FUSED prep launch: blocks 0..195 = cursor-free edge shuffle;
// blocks 196..977 = layer-1 MFMA GEMM (independent work, co-scheduled).
//
// Shuffle: LDS histogram + local scan; entries written bucket-grouped into
// the block's OWN slab tmp2[blk*CHUNK..] (no global atomics, no pre-zeroed
// state).  Counts/offsets stored bucket-major for k_sort's coalesced read.
//
// GEMM: one wave per 16-row strip, split-bf16 (hi*hi+hi*lo+lo*hi ~ fp32);
// h1 stored UNSCALED bf16 (dinv applied per-edge downstream).
__global__ __launch_bounds__(256) void k_prep(
        const int* __restrict__ src, const int* __restrict__ dst,
        int* __restrict__ lcnt_g, int* __restrict__ lofs_g,
        unsigned int* __restrict__ tmp2,
        const float* __restrict__ X,
        const ushort* __restrict__ wh, const ushort* __restrict__ wl,
        ushort* __restrict__ H1) {
    __shared__ int lcnt[256];
    __shared__ int lsc[256];
    __shared__ int lcur[256];
    int tid = threadIdx.x;
    if (blockIdx.x < 196) {
        int blk = blockIdx.x;
        lcnt[tid] = 0;
        __syncthreads();
        int e0 = blk * CHUNK;
        int e1 = e0 + CHUNK; if (e1 > NE) e1 = NE;
        for (int e = e0 + tid; e < e1; e += 256)
            atomicAdd(&lcnt[dst[e] >> 8], 1);
        __syncthreads();
        int v = lcnt[tid];
        lsc[tid] = v;
        __syncthreads();
        for (int o = 1; o < 256; o <<= 1) {
            int t = (tid >= o) ? lsc[tid - o] : 0;
            __syncthreads();
            lsc[tid] += t;
            __syncthreads();
        }
        int excl = lsc[tid] - v;
        lcnt_g[tid * 196 + blk] = v;
        lofs_g[tid * 196 + blk] = excl;
        lcur[tid] = excl;
        __syncthreads();
        for (int e = e0 + tid; e < e1; e += 256) {
            int d = dst[e], s = src[e];
            int b = d >> 8;
            int r = atomicAdd(&lcur[b], 1);
            tmp2[blk * CHUNK + r] = ((unsigned int)s << 8) | (unsigned int)(d & 255);
        }
        return;
    }
    // ---- GEMM half ----
    int wave = tid >> 6;
    int lane = tid & 63;
    int strip = (blockIdx.x - 196) * 4 + wave;
    if (strip >= NSTRIP) return;
    int rb = strip << 4;
    int m = lane & 15;
    int quad = lane >> 4;
    const float* ar = X + (size_t)(rb + m) * DD;
    f32x4 acc[8];
#pragma unroll
    for (int t = 0; t < 8; ++t) acc[t] = (f32x4){0.f, 0.f, 0.f, 0.f};
#pragma unroll
    for (int kk = 0; kk < 4; ++kk) {
        float4 xa = *(const float4*)(ar + kk * 32 + quad * 8);
        float4 xb = *(const float4*)(ar + kk * 32 + quad * 8 + 4);
        float xs[8] = {xa.x, xa.y, xa.z, xa.w, xb.x, xb.y, xb.z, xb.w};
        bf8_t ah, al;
#pragma unroll
        for (int j = 0; j < 8; ++j) {
            unsigned short hh = f2bf(xs[j]);
            ah[j] = (short)hh;
            al[j] = (short)f2bf(xs[j] - bf2f(hh));
        }
#pragma unroll
        for (int t = 0; t < 8; ++t) {
            size_t bo = ((size_t)(t * 4 + kk) * 64 + lane) * 8;
            bf8_t bh = *(const bf8_t*)(wh + bo);
            bf8_t bl = *(const bf8_t*)(wl + bo);
            acc[t] = __builtin_amdgcn_mfma_f32_16x16x32_bf16(ah, bh, acc[t], 0, 0, 0);
            acc[t] = __builtin_amdgcn_mfma_f32_16x16x32_bf16(ah, bl, acc[t], 0, 0, 0);
            acc[t] = __builtin_amdgcn_mfma_f32_16x16x32_bf16(al, bh, acc[t], 0, 0, 0);
        }
    }
    // C/D layout (m89-verified): col = lane&15, row = quad*4 + reg
#pragma unroll
    for (int t = 0; t < 8; ++t) {
#pragma unroll
        for (int r = 0; r < 4; ++r)
            H1[(size_t)(rb + quad * 4 + r) * DD + t * 16 + m] = f2bf(acc[t][r]);
    }
}

// per-bucket gather (binary search over the 196 block-runs) + LDS counting
// sort -> padded CSR slab, per-node (start,end), dinv.
__global__ __launch_bounds__(256) void k_sort(const int* __restrict__ lcnt_g,
                                              const int* __restrict__ lofs_g,
                                              const unsigned int* __restrict__ tmp2,
                                              ushort* __restrict__ csru,
                                              int2* __restrict__ offs2,
                                              float* __restrict__ dinv) {
    __shared__ unsigned int ent[MAXB];
    __shared__ int c[256];    // per-block count for this bucket
    __shared__ int p[256];    // inclusive prefix
    __shared__ int o[256];    // per-block local offset
    __shared__ int cnt[256];
    __shared__ int boff[256];
    __shared__ int cur[256];
    int b = blockIdx.x, tid = threadIdx.x;
    int cv = (tid < 196) ? lcnt_g[b * 196 + tid] : 0;
    o[tid] = (tid < 196) ? lofs_g[b * 196 + tid] : 0;
    c[tid] = cv;
    p[tid] = cv;
    cnt[tid] = 0;
    __syncthreads();
    for (int s = 1; s < 256; s <<= 1) {
        int t = (tid >= s) ? p[tid - s] : 0;
        __syncthreads();
        p[tid] += t;
        __syncthreads();
    }
    int nb = p[255];
    for (int i = tid; i < nb; i += 256) {
        // first blk with p[blk] > i
        int lo = 0, hi = 255;
#pragma unroll
        for (int it = 0; it < 8; ++it) {
            int mid = (lo + hi) >> 1;
            if (p[mid] > i) hi = mid; else lo = mid + 1;
        }
        int blk = lo;
        int j = i - (p[blk] - c[blk]);
        unsigned int e = tmp2[blk * CHUNK + o[blk] + j];
        ent[i] = e;
        atomicAdd(&cnt[e & 255], 1);
    }
    __syncthreads();
    int v = cnt[tid];
    boff[tid] = v;
    __syncthreads();
    for (int s = 1; s < 256; s <<= 1) {
        int t = (tid >= s) ? boff[tid - s] : 0;
        __syncthreads();
        boff[tid] += t;
        __syncthreads();
    }
    int excl = boff[tid] - v;
    int base = b * MAXB;
    int node = b * 256 + tid;
    if (node < NN) {
        offs2[node] = make_int2(base + excl, base + excl + v);
        dinv[node] = rsqrtf((float)(v + 1));   // +1 self-loop
    }
    cur[tid] = excl;
    __syncthreads();
    for (int i = tid; i < nb; i += 256) {
        unsigned int e = ent[i];
        int bin = e & 255;
        int r = atomicAdd(&cur[bin], 1);
        csru[base + r] = (ushort)(e >> 8);
    }
}

// FUSED layer-1 aggregation + layer-2 GEMM.  512 threads, one block = 16
// nodes.  Phase 1: 8 waves x 2 nodes; per-edge w = dinv[src] gather (h1 is
// unscaled); x2 row = relu(dinv_d*(sum + dinv_d*h1_d) + b1) -> LDS (pitch
// 136 floats: 16B-aligned, max 4-way bank alias).  Phase 2: barrier, each
// wave MFMAs ONE 16-col N-tile of the 16x128 strip vs W2; h2 unscaled bf16.
__global__ __launch_bounds__(512) void k_aggmm(const ushort* __restrict__ h1,
                                               const float* __restrict__ dinv,
                                               const int2* __restrict__ offs2,
                                               const ushort* __restrict__ csru,
                                               const float* __restrict__ b1,
                                               const ushort* __restrict__ w2h,
                                               const ushort* __restrict__ w2l,
                                               ushort* __restrict__ h2) {
    __shared__ float xs[16][136];
    int wave = threadIdx.x >> 6;
    int lane = threadIdx.x & 63;
    int rb = blockIdx.x * 16;
    int q = lane >> 4;
    int l = lane & 15;
    const float* bp = b1 + 8 * l;
    // ---- phase 1: 2 nodes per wave ----
    for (int nn = 0; nn < 2; ++nn) {
        int node = rb + wave * 2 + nn;
        float a0[8] = {0.f, 0.f, 0.f, 0.f, 0.f, 0.f, 0.f, 0.f};
        float a1[8] = {0.f, 0.f, 0.f, 0.f, 0.f, 0.f, 0.f, 0.f};
        float a2[8] = {0.f, 0.f, 0.f, 0.f, 0.f, 0.f, 0.f, 0.f};
        float a3[8] = {0.f, 0.f, 0.f, 0.f, 0.f, 0.f, 0.f, 0.f};
        int2 oe = offs2[node];
        int e  = oe.x + q;
        int e1 = oe.y;
        for (; e + 12 < e1; e += 16) {
            int s0 = csru[e];
            int s1 = csru[e + 4];
            int s2 = csru[e + 8];
            int s3 = csru[e + 12];
            float w0 = dinv[s0], w1 = dinv[s1], w2 = dinv[s2], w3 = dinv[s3];
            us8 v0 = *(const us8*)(h1 + (size_t)s0 * DD + 8 * l);
            us8 v1 = *(const us8*)(h1 + (size_t)s1 * DD + 8 * l);
            us8 v2 = *(const us8*)(h1 + (size_t)s2 * DD + 8 * l);
            us8 v3 = *(const us8*)(h1 + (size_t)s3 * DD + 8 * l);
#pragma unroll
            for (int j = 0; j < 8; ++j) {
                a0[j] += w0 * bf2f(v0[j]);
                a1[j] += w1 * bf2f(v1[j]);
                a2[j] += w2 * bf2f(v2[j]);
                a3[j] += w3 * bf2f(v3[j]);
            }
        }
        for (; e < e1; e += 4) {
            int s0 = csru[e];
            float w0 = dinv[s0];
            us8 v0 = *(const us8*)(h1 + (size_t)s0 * DD + 8 * l);
#pragma unroll
            for (int j = 0; j < 8; ++j) a0[j] += w0 * bf2f(v0[j]);
        }
        float dnode = dinv[node];
        if (q == 0) {  // self-loop term dinv_d*h1_d, counted once
            us8 v = *(const us8*)(h1 + (size_t)node * DD + 8 * l);
#pragma unroll
            for (int j = 0; j < 8; ++j) a0[j] += dnode * bf2f(v[j]);
        }
#pragma unroll
        for (int j = 0; j < 8; ++j) {
            a0[j] += a1[j] + a2[j] + a3[j];
            a0[j] += __shfl_xor(a0[j], 16, 64);
            a0[j] += __shfl_xor(a0[j], 32, 64);
        }
        if (q == 0) {
            float* xr = &xs[wave * 2 + nn][8 * l];
#pragma unroll
            for (int j = 0; j < 8; ++j)
                xr[j] = fmaxf(dnode * a0[j] + bp[j], 0.f);
        }
    }
    __syncthreads();
    // ---- phase 2: each wave does N-tile t = wave ----
    int m = lane & 15;
    int quad = lane >> 4;
    int t = wave;
    f32x4 acc = (f32x4){0.f, 0.f, 0.f, 0.f};
#pragma unroll
    for (int kk = 0; kk < 4; ++kk) {
        const float* xr = &xs[m][kk * 32 + quad * 8];
        float4 xa = *(const float4*)xr;
        float4 xb = *(const float4*)(xr + 4);
        float xv[8] = {xa.x, xa.y, xa.z, xa.w, xb.x, xb.y, xb.z, xb.w};
        bf8_t ah, al;
#pragma unroll
        for (int j = 0; j < 8; ++j) {
            unsigned short hh = f2bf(xv[j]);
            ah[j] = (short)hh;
            al[j] = (short)f2bf(xv[j] - bf2f(hh));
        }
        size_t bo = ((size_t)(t * 4 + kk) * 64 + lane) * 8;
        bf8_t bh = *(const bf8_t*)(w2h + bo);
        bf8_t bl = *(const bf8_t*)(w2l + bo);
        acc = __builtin_amdgcn_mfma_f32_16x16x32_bf16(ah, bh, acc, 0, 0, 0);
        acc = __builtin_amdgcn_mfma_f32_16x16x32_bf16(ah, bl, acc, 0, 0, 0);
        acc = __builtin_amdgcn_mfma_f32_16x16x32_bf16(al, bh, acc, 0, 0, 0);
    }
#pragma unroll
    for (int r = 0; r < 4; ++r)
        h2[(size_t)(rb + quad * 4 + r) * DD + t * 16 + m] = f2bf(acc[r]);
}

// final aggregation: out[i] = relu( dinv_i*(sum dinv_s*h2_s + dinv_i*h2_i) + b2 )
__global__ void k_agg(const ushort* __restrict__ h, const float* __restrict__ dinv,
                      const int2* __restrict__ offs2, const ushort* __restrict__ csru,
                      const float* __restrict__ bias, float* __restrict__ outf) {
    int wave = threadIdx.x >> 6;
    int lane = threadIdx.x & 63;
    int node = blockIdx.x * 4 + wave;   // grid = NN/4 exactly
    int q = lane >> 4;
    int l = lane & 15;
    float a0[8] = {0.f, 0.f, 0.f, 0.f, 0.f, 0.f, 0.f, 0.f};
    float a1[8] = {0.f, 0.f, 0.f, 0.f, 0.f, 0.f, 0.f, 0.f};
    float a2[8] = {0.f, 0.f, 0.f, 0.f, 0.f, 0.f, 0.f, 0.f};
    float a3[8] = {0.f, 0.f, 0.f, 0.f, 0.f, 0.f, 0.f, 0.f};
    int2 oe = offs2[node];
    int e  = oe.x + q;
    int e1 = oe.y;
    for (; e + 12 < e1; e += 16) {
        int s0 = csru[e];
        int s1 = csru[e + 4];
        int s2 = csru[e + 8];
        int s3 = csru[e + 12];
        float w0 = dinv[s0], w1 = dinv[s1], w2 = dinv[s2], w3 = dinv[s3];
        us8 v0 = *(const us8*)(h + (size_t)s0 * DD + 8 * l);
        us8 v1 = *(const us8*)(h + (size_t)s1 * DD + 8 * l);
        us8 v2 = *(const us8*)(h + (size_t)s2 * DD + 8 * l);
        us8 v3 = *(const us8*)(h + (size_t)s3 * DD + 8 * l);
#pragma unroll
        for (int j = 0; j < 8; ++j) {
            a0[j] += w0 * bf2f(v0[j]);
            a1[j] += w1 * bf2f(v1[j]);
            a2[j] += w2 * bf2f(v2[j]);
            a3[j] += w3 * bf2f(v3[j]);
        }
    }
    for (; e < e1; e += 4) {
        int s0 = csru[e];
        float w0 = dinv[s0];
        us8 v0 = *(const us8*)(h + (size_t)s0 * DD + 8 * l);
#pragma unroll
        for (int j = 0; j < 8; ++j) a0[j] += w0 * bf2f(v0[j]);
    }
    float dnode = dinv[node];
    if (q == 0) {  // self-loop term
        us8 v = *(const us8*)(h + (size_t)node * DD + 8 * l);
#pragma unroll
        for (int j = 0; j < 8; ++j) a0[j] += dnode * bf2f(v[j]);
    }
#pragma unroll
    for (int j = 0; j < 8; ++j) {
        a0[j] += a1[j] + a2[j] + a3[j];
        a0[j] += __shfl_xor(a0[j], 16, 64);
        a0[j] += __shfl_xor(a0[j], 32, 64);
    }
    if (q == 0) {
        float* op = outf + (size_t)node * DD + 8 * l;
        const float* bp = bias + 8 * l;
        float4 o0, o1;
        o0.x = fmaxf(dnode * a0[0] + bp[0], 0.f);
        o0.y = fmaxf(dnode * a0[1] + bp[1], 0.f);
        o0.z = fmaxf(dnode * a0[2] + bp[2], 0.f);
        o0.w = fmaxf(dnode * a0[3] + bp[3], 0.f);
        o1.x = fmaxf(dnode * a0[4] + bp[4], 0.f);
        o1.y = fmaxf(dnode * a0[5] + bp[5], 0.f);
        o1.z = fmaxf(dnode * a0[6] + bp[6], 0.f);
        o1.w = fmaxf(dnode * a0[7] + bp[7], 0.f);
        *(float4*)op = o0;
        *(float4*)(op + 4) = o1;
    }
}

extern "C" void kernel_launch(void* const* d_in, const int* in_sizes, int n_in,
                              void* d_out, int out_size, void* d_ws, size_t ws_size,
                              hipStream_t stream) {
    const float* x  = (const float*)d_in[0];
    const int*   ei = (const int*)d_in[1];
    const float* W1 = (const float*)d_in[2];
    const float* b1 = (const float*)d_in[3];
    const float* W2 = (const float*)d_in[4];
    const float* b2 = (const float*)d_in[5];
    float* out = (float*)d_out;

    const int* src = ei;        // edge_index[0]
    const int* dst = ei + NE;   // edge_index[1]

    int*          wsi  = (int*)d_ws;
    float*        wsf  = (float*)d_ws;
    ushort*       wsu  = (ushort*)d_ws;
    unsigned int* wsuw = (unsigned int*)d_ws;
    int*    lcnt_g = wsi + OF_LCNT;
    int*    lofs_g = wsi + OF_LOFS;
    float*  dinv   = wsf + OF_DINV;
    int2*   offs2  = (int2*)(wsi + OF_OFFS2);
    unsigned int* tmp2 = wsuw + OF_TMP2;
    ushort* csru   = wsu + (size_t)OF_CSRU * 2;
    ushort* h1     = wsu + (size_t)OF_H1 * 2;
    ushort* h2     = wsu + (size_t)OF_H2 * 2;
    ushort* w1h    = wsu + (size_t)OF_W1H * 2;
    ushort* w1l    = wsu + (size_t)OF_W1L * 2;
    ushort* w2h    = wsu + (size_t)OF_W2H * 2;
    ushort* w2l    = wsu + (size_t)OF_W2L * 2;

    // 1: W split tables (needed by k_prep's GEMM half)
    hipLaunchKernelGGL(k_wconv, dim3(16), dim3(256), 0, stream,
                       W1, W2, w1h, w1l, w2h, w2l);
    // 2: edge shuffle (196 blocks)  ||  layer-1 GEMM (782 blocks)
    hipLaunchKernelGGL(k_prep, dim3(196 + (NSTRIP + 3) / 4), dim3(256), 0, stream,
                       src, dst, lcnt_g, lofs_g, tmp2, x, w1h, w1l, h1);
    // 3: per-bucket sort -> CSR + offs2 + dinv
    hipLaunchKernelGGL(k_sort, dim3(NB), dim3(256), 0, stream,
                       lcnt_g, lofs_g, tmp2, csru, offs2, dinv);
    // 4: fused agg(L1)+relu+b1 -> @W2 -> h2
    hipLaunchKernelGGL(k_aggmm, dim3(NSTRIP), dim3(512), 0, stream,
                       h1, dinv, offs2, csru, b1, w2h, w2l, h2);
    // 5: final aggregation -> out
    hipLaunchKernelGGL(k_agg, dim3(NN / 4), dim3(256), 0, stream,
                       h2, dinv, offs2, csru, b2, out);
}